// Round 11
// baseline (338.003 us; speedup 1.0000x reference)
//
#include <hip/hip_runtime.h>

// PaDiM training-branch accumulation + finalize — FULLY FUSED single kernel.
// embeddings: [B=32, C=192, P=3136] f32; means: [P,C] f32; covariances: [P,C,C] f32; n: int
// out: learned_means [P,C] ++ learned_covs [P,C,C]
//
// R11: one kernel, 2 patches/block (grid 1568). R6/R9/R10 all converged at
// 215-225us with K2 streaming ~5.2TB/s + K1 ~25-30us serial + Et round-trip.
// This removes K1 and Et entirely:
//  - stage: 24 independent float2 loads/thread (emb rows, 8B granule); the
//    64B line spans 8 adjacent swizzled blocks (same XCD, ~co-resident) so
//    L2 absorbs the granule amp -> ~77MB emb HBM fetch.
//  - LDS emb tile [2][192][40 ushort]: 80B row stride -> conflict-free
//    ds_read_b128 frags (64B rows would be 8-way conflicted; 80B = 16B-
//    aligned and 20c%32 spreads banks).
//  - compute: R9's PROVEN wave engine per patch: wave w owns d-cols
//    [48w,48w+48), 12 c-tiles, 1 B-frag ds_read + 3 MFMA + wave-private
//    LDS transpose + fused finalize per tile, 3-slot rolling cov prefetch.
//  - cov loads nt (don't evict emb lines from L2); emb loads plain;
//    stores plain (R9-proven exact WRITE_SIZE; R8's nt stores doubled it).

#define BB 32
#define CC 192
#define PP 3136
#define EPSV 0.01f
#define WROW 52        // padded row stride (floats) of wave transpose buffer

typedef float f32x4 __attribute__((ext_vector_type(4)));
typedef short bf16x8 __attribute__((ext_vector_type(8)));

__device__ __forceinline__ unsigned short f2bf(float f) {
    unsigned int u = __float_as_uint(f);
    u += 0x7fffu + ((u >> 16) & 1u);        // round-to-nearest-even
    return (unsigned short)(u >> 16);
}
__device__ __forceinline__ float bf16val(unsigned short u) {
    return __uint_as_float(((unsigned int)u) << 16);
}

__global__ __launch_bounds__(256, 3) void padim_fused(
    const float* __restrict__ emb,    // [B,C,P]
    const float* __restrict__ means,  // [P,C]
    const float* __restrict__ covs,   // [P,C,C]
    const int*   __restrict__ n_ptr,  // [1]
    float* __restrict__ out_means,    // [P,C]
    float* __restrict__ out_covs)     // [P,C,C]
{
    // 80B rows: 32 bf16 data + 8 pad ushorts. 2*192*80 = 30720 B.
    __shared__ unsigned short eb[2][CC][40];
    __shared__ __align__(16) float m_lds[2][CC];            // 1536 B
    __shared__ __align__(16) float wbuf[4][16 * WROW];      // 13312 B
    // total 45568 B -> 3 blocks/CU

    // XCD-bijective swizzle over 1568 blocks (1568%8==0): 8 adjacent sw
    // blocks (= one 64B emb line = 16 patches) land on the same XCD.
    const int bid = blockIdx.x;
    const int sw = (bid & 7) * (PP / 2 / 8) + (bid >> 3);   // 196 per XCD
    const int p0 = sw * 2;

    const int t = threadIdx.x;
    const int lane = t & 63;
    const int w = t >> 6;                 // wave 0..3: owns cov cols [48w,48w+48)
    const int l15 = lane & 15;
    const int l4  = lane >> 4;

    const float n_new = (float)(n_ptr[0] + BB);       // 128
    const float inv_nnew = 1.0f / n_new;
    const float inv_nm1 = 1.0f / (n_new - 1.0f);      // 1/127

    // ---- Stage: 24 independent float2 loads/thread, bf16-convert to LDS ----
    #pragma unroll 8
    for (int k = 0; k < 24; ++k) {
        const int i = k * 256 + t;        // row index b*CC + c, 0..6143
        const int b = i / CC;
        const int c = i - b * CC;
        const float2 v = *reinterpret_cast<const float2*>(&emb[(size_t)i * PP + p0]);
        eb[0][c][b] = f2bf(v.x);
        eb[1][c][b] = f2bf(v.y);
    }
    __syncthreads();

    // ---- Means: thread handles rows r, r+256 of the 384 (j,c) pairs ----
    for (int r = t; r < 2 * CC; r += 256) {
        const int j = r / CC;
        const int c = r - j * CC;
        float s = 0.f;
        #pragma unroll
        for (int q = 0; q < 16; ++q) {
            const unsigned int u = *reinterpret_cast<const unsigned int*>(&eb[j][c][2 * q]);
            s += bf16val((unsigned short)(u & 0xffffu)) + bf16val((unsigned short)(u >> 16));
        }
        const size_t idx = (size_t)(p0 + j) * CC + c;
        const float mm = (means[idx] + s) * inv_nnew;
        m_lds[j][c] = mm;
        out_means[idx] = mm;
    }
    __syncthreads();   // last block-wide barrier; waves drift from here on

    // ---- Per-lane epilogue geometry (patch-invariant) ----
    // [16 rows][12 chunks of 16B] per tile; chunk = k*64 + lane.
    int rk[3], qk[3], offb[3];
    #pragma unroll
    for (int k = 0; k < 3; ++k) {
        const int chunk = k * 64 + lane;
        rk[k] = chunk / 12;
        qk[k] = chunk - rk[k] * 12;
        offb[k] = rk[k] * CC + 48 * w + 4 * qk[k];
    }

    // ---- Per patch: frags -> 12 c-tiles of {B ds_read, 3 MFMA, LDS
    //      transpose, fused finalize RMW}, 3-slot rolling cov prefetch ----
    #pragma unroll 1
    for (int j = 0; j < 2; ++j) {
        const float* __restrict__ cov_p = covs + (size_t)(p0 + j) * CC * CC;
        float* __restrict__ out_p = out_covs + (size_t)(p0 + j) * CC * CC;
        const float* __restrict__ mj = &m_lds[j][0];

        // A frags: d-rows (3w+dt)*16 + l15, one 16B LDS read each
        bf16x8 Af[3];
        #pragma unroll
        for (int dt = 0; dt < 3; ++dt)
            Af[dt] = *reinterpret_cast<const bf16x8*>(&eb[j][(3 * w + dt) * 16 + l15][l4 * 8]);

        f32x4 mdk[3];
        #pragma unroll
        for (int k = 0; k < 3; ++k)
            mdk[k] = *reinterpret_cast<const f32x4*>(&mj[48 * w + 4 * qk[k]]);

        // rolling cov prefetch ring (tiles ct, ct+1 in flight)
        f32x4 cin[3][3];
        #pragma unroll
        for (int pt = 0; pt < 2; ++pt)
            #pragma unroll
            for (int k = 0; k < 3; ++k)
                cin[pt][k] = __builtin_nontemporal_load(reinterpret_cast<const f32x4*>(
                    cov_p + (size_t)(pt * 16) * CC + offb[k]));

        #pragma unroll
        for (int ct = 0; ct < 12; ++ct) {
            if (ct < 10) {
                const int ring2 = (ct + 2) % 3;
                #pragma unroll
                for (int k = 0; k < 3; ++k)
                    cin[ring2][k] = __builtin_nontemporal_load(reinterpret_cast<const f32x4*>(
                        cov_p + (size_t)((ct + 2) * 16) * CC + offb[k]));
            }
            // B frag: c-rows ct*16 + l15
            const bf16x8 Bf = *reinterpret_cast<const bf16x8*>(&eb[j][ct * 16 + l15][l4 * 8]);
            f32x4 a[3];
            #pragma unroll
            for (int dt = 0; dt < 3; ++dt)
                a[dt] = __builtin_amdgcn_mfma_f32_16x16x32_bf16(
                    Af[dt], Bf, (f32x4){0.f, 0.f, 0.f, 0.f}, 0, 0, 0);

            // wave-private transpose: acc(c=cbase+l15, d=48w+dt*16+l4*4+reg)
            #pragma unroll
            for (int dt = 0; dt < 3; ++dt)
                *reinterpret_cast<f32x4*>(&wbuf[w][l15 * WROW + (dt * 4 + l4) * 4]) = a[dt];

            const int cbase = ct * 16;
            const int ring = ct % 3;
            #pragma unroll
            for (int k = 0; k < 3; ++k) {
                const f32x4 av = *reinterpret_cast<const f32x4*>(&wbuf[w][rk[k] * WROW + 4 * qk[k]]);
                const int c = cbase + rk[k];
                const float nmc = n_new * mj[c];
                f32x4 o = (cin[ring][k] + av - nmc * mdk[k]) * inv_nm1;
                const int dd = c - (48 * w + 4 * qk[k]);   // diagonal when 0<=dd<4
                o.x += (dd == 0) ? EPSV : 0.f;
                o.y += (dd == 1) ? EPSV : 0.f;
                o.z += (dd == 2) ? EPSV : 0.f;
                o.w += (dd == 3) ? EPSV : 0.f;
                *reinterpret_cast<f32x4*>(out_p + (size_t)cbase * CC + offb[k]) = o;
            }
        }
    }
}

extern "C" void kernel_launch(void* const* d_in, const int* in_sizes, int n_in,
                              void* d_out, int out_size, void* d_ws, size_t ws_size,
                              hipStream_t stream) {
    const float* emb   = (const float*)d_in[0];
    const float* means = (const float*)d_in[1];
    const float* covs  = (const float*)d_in[2];
    const int*   n_ptr = (const int*)d_in[3];

    float* out_means = (float*)d_out;                      // [P,C]
    float* out_covs  = (float*)d_out + (size_t)PP * CC;    // [P,C,C]

    hipLaunchKernelGGL(padim_fused, dim3(PP / 2), dim3(256), 0, stream,
                       emb, means, covs, n_ptr, out_means, out_covs);
}

// Round 12
// 204.495 us; speedup vs baseline: 1.6529x; 1.6529x over previous
//
#include <hip/hip_runtime.h>

// PaDiM training-branch accumulation + finalize.
// embeddings: [B=32, C=192, P=3136] f32; means: [P,C] f32; covariances: [P,C,C] f32; n: int
// out: learned_means [P,C] ++ learned_covs [P,C,C]
//
// R12 = R6 (best measured: 215.7us) + bf16 Et.
//   R6 proven bits kept verbatim: slab-split grid (PP,2), LB(256,4), fp32
//   register SYRK 6x12 from flat f32 E[II] LDS, nt cov loads, nt 256B-segment
//   stores (measured byte-exact WRITE_SIZE in R5), XCD swizzle in K1 grid.
//   New: Et is bf16 [P][II] (38.5MB, halves K1 write + K2 Et read); K2
//   stages via 3 uint4 loads/thread + bf16->f32 unpack into E[II].
//   R11 lessons: no scalar u16 LDS writes, no reg-ring that can spill.

#define BB 32
#define CC 192
#define PP 3136
#define II (BB * CC)   // 6144
#define EPSV 0.01f

typedef float nat_float4 __attribute__((ext_vector_type(4)));

__device__ __forceinline__ unsigned short f2bf(float f) {
    unsigned int u = __float_as_uint(f);
    u += 0x7fffu + ((u >> 16) & 1u);        // round-to-nearest-even
    return (unsigned short)(u >> 16);
}

// ---------- Kernel 1: tiled transpose emb [II][PP] f32 -> Et [PP][II] bf16 ----------
__global__ __launch_bounds__(256) void transpose_kernel(
    const float* __restrict__ emb, unsigned short* __restrict__ Et)
{
    __shared__ float tile[64][65];          // +1 pad: conflict-free col reads
    const int i0 = blockIdx.x * 64;         // 96 tiles over II
    const int p0 = blockIdx.y * 64;         // 49 tiles over PP
    const int t = threadIdx.x;
    const int tc = t & 63;                  // fast index (coalesced)
    const int tr4 = t >> 6;                 // 0..3

    #pragma unroll
    for (int k = 0; k < 16; ++k) {
        const int r = k * 4 + tr4;          // i-local row
        tile[r][tc] = __builtin_nontemporal_load(&emb[(size_t)(i0 + r) * PP + (p0 + tc)]);
    }
    __syncthreads();

    // Write: 8 iters; lanes pack 2 bf16 -> u32. Per instr: 2 rows x 128B.
    const int q = tc & 31;                  // i-pair index 0..31
    const int hf = tc >> 5;                 // 0..1
    #pragma unroll
    for (int k = 0; k < 8; ++k) {
        const int prow = k * 8 + tr4 * 2 + hf;   // p-local row 0..63
        const unsigned int lo = (unsigned int)f2bf(tile[2 * q][prow]);
        const unsigned int hi = (unsigned int)f2bf(tile[2 * q + 1][prow]);
        unsigned int* dst = reinterpret_cast<unsigned int*>(
            Et + (size_t)(p0 + prow) * II + i0);
        dst[q] = lo | (hi << 16);
    }
}

// ---------- Kernel 2: per-patch-slab fp32 SYRK + finalize (R6 engine) ----------
__global__ __launch_bounds__(256, 4) void padim_main(
    const unsigned short* __restrict__ Et,  // [P][II] bf16
    const float* __restrict__ means,        // [P,C]
    const float* __restrict__ covs,         // [P,C,C]
    const int*   __restrict__ n_ptr,        // [1]
    float* __restrict__ out_means,          // [P,C]
    float* __restrict__ out_covs)           // [P,C,C]
{
    __shared__ __align__(16) float E[II];   // 24 KB, flat [b*CC + c]
    __shared__ __align__(16) float m[CC];

    const int p = blockIdx.x;
    const int slab = blockIdx.y;            // 0: rows 0..95, 1: rows 96..191
    const int t = threadIdx.x;

    const float n_new = (float)(n_ptr[0] + BB);       // 128
    const float inv_nnew = 1.0f / n_new;
    const float inv_nm1 = 1.0f / (n_new - 1.0f);      // 1/127

    // ---- Stage Et[p] (bf16) -> E (f32): 3 coalesced uint4 loads/thread ----
    {
        const uint4* __restrict__ src = reinterpret_cast<const uint4*>(Et + (size_t)p * II);
        #pragma unroll
        for (int k = 0; k < 3; ++k) {
            const int idx = k * 256 + t;            // 0..767 (16B chunks)
            const uint4 v = src[idx];
            float f[8];
            f[0] = __uint_as_float(v.x << 16); f[1] = __uint_as_float(v.x & 0xffff0000u);
            f[2] = __uint_as_float(v.y << 16); f[3] = __uint_as_float(v.y & 0xffff0000u);
            f[4] = __uint_as_float(v.z << 16); f[5] = __uint_as_float(v.z & 0xffff0000u);
            f[6] = __uint_as_float(v.w << 16); f[7] = __uint_as_float(v.w & 0xffff0000u);
            float4* dst = reinterpret_cast<float4*>(&E[idx * 8]);
            dst[0] = make_float4(f[0], f[1], f[2], f[3]);
            dst[1] = make_float4(f[4], f[5], f[6], f[7]);
        }
    }
    __syncthreads();

    // ---- Means (both slabs compute; slab 0 writes) ----
    if (t < CC) {
        float s = 0.0f;
        #pragma unroll
        for (int b = 0; b < BB; ++b) s += E[b * CC + t];
        const float mm = (means[(size_t)p * CC + t] + s) * inv_nnew;
        m[t] = mm;
        if (slab == 0) out_means[(size_t)p * CC + t] = mm;
    }
    __syncthreads();

    const int tx = t & 15;   // d: 3 groups of cols g*64 + tx*4
    const int ty = t >> 4;   // c: 6 rows within this slab's 96
    const int dbase0 = tx * 4;
    const int c0 = slab * 96 + ty * 6;

    const float* __restrict__ cov_p = covs + (size_t)p * CC * CC;
    float* __restrict__ out_p = out_covs + (size_t)p * CC * CC;

    float md[12];
    *reinterpret_cast<float4*>(&md[0]) = *reinterpret_cast<const float4*>(&m[dbase0]);
    *reinterpret_cast<float4*>(&md[4]) = *reinterpret_cast<const float4*>(&m[64 + dbase0]);
    *reinterpret_cast<float4*>(&md[8]) = *reinterpret_cast<const float4*>(&m[128 + dbase0]);

    float acc[6][12];
    #pragma unroll
    for (int i = 0; i < 6; ++i)
        #pragma unroll
        for (int j = 0; j < 12; ++j) acc[i][j] = 0.f;

    #pragma unroll 4
    for (int b = 0; b < BB; ++b) {
        const float* __restrict__ Eb = E + b * CC;
        float cs[6], ds[12];
        *reinterpret_cast<float4*>(&ds[0]) = *reinterpret_cast<const float4*>(&Eb[dbase0]);
        *reinterpret_cast<float4*>(&ds[4]) = *reinterpret_cast<const float4*>(&Eb[64 + dbase0]);
        *reinterpret_cast<float4*>(&ds[8]) = *reinterpret_cast<const float4*>(&Eb[128 + dbase0]);
        *reinterpret_cast<float2*>(&cs[0]) = *reinterpret_cast<const float2*>(&Eb[c0]);
        *reinterpret_cast<float2*>(&cs[2]) = *reinterpret_cast<const float2*>(&Eb[c0 + 2]);
        *reinterpret_cast<float2*>(&cs[4]) = *reinterpret_cast<const float2*>(&Eb[c0 + 4]);
        #pragma unroll
        for (int i = 0; i < 6; ++i)
            #pragma unroll
            for (int j = 0; j < 12; ++j)
                acc[i][j] = fmaf(cs[i], ds[j], acc[i][j]);
    }

    float mc[6];
    *reinterpret_cast<float2*>(&mc[0]) = *reinterpret_cast<const float2*>(&m[c0]);
    *reinterpret_cast<float2*>(&mc[2]) = *reinterpret_cast<const float2*>(&m[c0 + 2]);
    *reinterpret_cast<float2*>(&mc[4]) = *reinterpret_cast<const float2*>(&m[c0 + 4]);

    // ---- Fused finalize + cov RMW stream (nt in, nt out; 256B segments) ----
    #pragma unroll
    for (int i = 0; i < 6; ++i) {
        const int c = c0 + i;
        const size_t row = (size_t)c * CC;
        const float nmc = n_new * mc[i];
        #pragma unroll
        for (int g = 0; g < 3; ++g) {
            const int db = g * 64 + dbase0;
            const nat_float4 cin = __builtin_nontemporal_load(
                reinterpret_cast<const nat_float4*>(&cov_p[row + db]));
            nat_float4 o;
            o.x = (cin.x + acc[i][g*4+0] - nmc * md[g*4+0]) * inv_nm1;
            o.y = (cin.y + acc[i][g*4+1] - nmc * md[g*4+1]) * inv_nm1;
            o.z = (cin.z + acc[i][g*4+2] - nmc * md[g*4+2]) * inv_nm1;
            o.w = (cin.w + acc[i][g*4+3] - nmc * md[g*4+3]) * inv_nm1;
            const int dd = c - db;   // diagonal hits when 0 <= dd < 4
            if (dd == 0) o.x += EPSV;
            if (dd == 1) o.y += EPSV;
            if (dd == 2) o.z += EPSV;
            if (dd == 3) o.w += EPSV;
            __builtin_nontemporal_store(o, reinterpret_cast<nat_float4*>(&out_p[row + db]));
        }
    }
}

// ---------- Fallback (ws too small): single-kernel with direct gather ----
__global__ __launch_bounds__(256, 3) void padim_fallback(
    const float* __restrict__ emb, const float* __restrict__ means,
    const float* __restrict__ covs, const int* __restrict__ n_ptr,
    float* __restrict__ out_means, float* __restrict__ out_covs)
{
    __shared__ __align__(16) float E[II];
    __shared__ __align__(16) float m[CC];
    const int bid = blockIdx.x;
    const int p = (bid & 7) * (PP / 8) + (bid >> 3);
    const int t = threadIdx.x;
    const float n_new = (float)(n_ptr[0] + BB);
    const float inv_nnew = 1.0f / n_new;
    const float inv_nm1 = 1.0f / (n_new - 1.0f);
    #pragma unroll
    for (int k = 0; k < II / 256; ++k) {
        const int i = t + k * 256;
        E[i] = emb[(size_t)i * PP + p];
    }
    __syncthreads();
    if (t < CC) {
        float s = 0.0f;
        #pragma unroll
        for (int b = 0; b < BB; ++b) s += E[b * CC + t];
        const float mm = (means[(size_t)p * CC + t] + s) * inv_nnew;
        m[t] = mm;
        out_means[(size_t)p * CC + t] = mm;
    }
    __syncthreads();
    const int tx = t & 15, ty = t >> 4;
    const int dbase0 = tx * 4;
    const float* __restrict__ cov_p = covs + (size_t)p * CC * CC;
    float* __restrict__ out_p = out_covs + (size_t)p * CC * CC;
    float md[12];
    *reinterpret_cast<float4*>(&md[0]) = *reinterpret_cast<const float4*>(&m[dbase0]);
    *reinterpret_cast<float4*>(&md[4]) = *reinterpret_cast<const float4*>(&m[64 + dbase0]);
    *reinterpret_cast<float4*>(&md[8]) = *reinterpret_cast<const float4*>(&m[128 + dbase0]);
    #pragma unroll
    for (int pass = 0; pass < 2; ++pass) {
        const int c0 = pass * 96 + ty * 6;
        float acc[6][12];
        #pragma unroll
        for (int i = 0; i < 6; ++i)
            #pragma unroll
            for (int j = 0; j < 12; ++j) acc[i][j] = 0.f;
        #pragma unroll 4
        for (int b = 0; b < BB; ++b) {
            const float* __restrict__ Eb = E + b * CC;
            float cs[6], ds[12];
            *reinterpret_cast<float4*>(&ds[0]) = *reinterpret_cast<const float4*>(&Eb[dbase0]);
            *reinterpret_cast<float4*>(&ds[4]) = *reinterpret_cast<const float4*>(&Eb[64 + dbase0]);
            *reinterpret_cast<float4*>(&ds[8]) = *reinterpret_cast<const float4*>(&Eb[128 + dbase0]);
            *reinterpret_cast<float2*>(&cs[0]) = *reinterpret_cast<const float2*>(&Eb[c0]);
            *reinterpret_cast<float2*>(&cs[2]) = *reinterpret_cast<const float2*>(&Eb[c0 + 2]);
            *reinterpret_cast<float2*>(&cs[4]) = *reinterpret_cast<const float2*>(&Eb[c0 + 4]);
            #pragma unroll
            for (int i = 0; i < 6; ++i)
                #pragma unroll
                for (int j = 0; j < 12; ++j)
                    acc[i][j] = fmaf(cs[i], ds[j], acc[i][j]);
        }
        float mc[6];
        *reinterpret_cast<float2*>(&mc[0]) = *reinterpret_cast<const float2*>(&m[c0]);
        *reinterpret_cast<float2*>(&mc[2]) = *reinterpret_cast<const float2*>(&m[c0 + 2]);
        *reinterpret_cast<float2*>(&mc[4]) = *reinterpret_cast<const float2*>(&m[c0 + 4]);
        #pragma unroll
        for (int i = 0; i < 6; ++i) {
            const int c = c0 + i;
            const size_t row = (size_t)c * CC;
            const float nmc = n_new * mc[i];
            #pragma unroll
            for (int g = 0; g < 3; ++g) {
                const int db = g * 64 + dbase0;
                const float4 cin = *reinterpret_cast<const float4*>(&cov_p[row + db]);
                float4 o;
                o.x = (cin.x + acc[i][g*4+0] - nmc * md[g*4+0]) * inv_nm1;
                o.y = (cin.y + acc[i][g*4+1] - nmc * md[g*4+1]) * inv_nm1;
                o.z = (cin.z + acc[i][g*4+2] - nmc * md[g*4+2]) * inv_nm1;
                o.w = (cin.w + acc[i][g*4+3] - nmc * md[g*4+3]) * inv_nm1;
                const int dd = c - db;
                if (dd == 0) o.x += EPSV;
                if (dd == 1) o.y += EPSV;
                if (dd == 2) o.z += EPSV;
                if (dd == 3) o.w += EPSV;
                *reinterpret_cast<float4*>(&out_p[row + db]) = o;
            }
        }
    }
}

extern "C" void kernel_launch(void* const* d_in, const int* in_sizes, int n_in,
                              void* d_out, int out_size, void* d_ws, size_t ws_size,
                              hipStream_t stream) {
    const float* emb   = (const float*)d_in[0];
    const float* means = (const float*)d_in[1];
    const float* covs  = (const float*)d_in[2];
    const int*   n_ptr = (const int*)d_in[3];

    float* out_means = (float*)d_out;                      // [P,C]
    float* out_covs  = (float*)d_out + (size_t)PP * CC;    // [P,C,C]

    const size_t et_bytes = (size_t)PP * II * sizeof(unsigned short);   // 38.5 MB
    if (ws_size >= et_bytes) {
        unsigned short* Et = (unsigned short*)d_ws;
        hipLaunchKernelGGL(transpose_kernel, dim3(II / 64, PP / 64), dim3(256),
                           0, stream, emb, Et);
        hipLaunchKernelGGL(padim_main, dim3(PP, 2), dim3(256), 0, stream,
                           Et, means, covs, n_ptr, out_means, out_covs);
    } else {
        hipLaunchKernelGGL(padim_fallback, dim3(PP), dim3(256), 0, stream,
                           emb, means, covs, n_ptr, out_means, out_covs);
    }
}